// Round 5
// baseline (237.243 us; speedup 1.0000x reference)
//
#include <hip/hip_runtime.h>
#include <math.h>

using u16 = unsigned short;
typedef __attribute__((ext_vector_type(8))) __bf16 bf16x8;
typedef __attribute__((ext_vector_type(4))) float f32x4;
typedef __attribute__((ext_vector_type(4))) float f4v;
typedef __attribute__((ext_vector_type(8))) u16 u16x8;

__device__ __forceinline__ u16 f2bf(float f) {
  unsigned u = __float_as_uint(f);
  u += 0x7fffu + ((u >> 16) & 1u);   // round-to-nearest-even
  return (u16)(u >> 16);
}

__device__ __forceinline__ void gload16(const void* g, void* l) {
  __builtin_amdgcn_global_load_lds(
      (const __attribute__((address_space(1))) unsigned int*)g,
      (__attribute__((address_space(3))) unsigned int*)l, 16, 0, 0);
}

__device__ __forceinline__ f32x4 MF(bf16x8 a, bf16x8 b, f32x4 c) {
  return __builtin_amdgcn_mfma_f32_16x16x32_bf16(a, b, c, 0, 0, 0);
}

// ---------------------------------------------------------------- cast f32->bf16 (weights only)
__global__ __launch_bounds__(256) void cast3_f32_bf16(
    const float* __restrict__ p0, const float* __restrict__ p1,
    const float* __restrict__ p2, u16* __restrict__ out, size_t ostride) {
  int z = blockIdx.z;
  const float* in = (z == 0) ? p0 : (z == 1) ? p1 : p2;
  size_t i = ((size_t)blockIdx.x * 256 + threadIdx.x) * 8;
  f4v a = *reinterpret_cast<const f4v*>(in + i);
  f4v b = *reinterpret_cast<const f4v*>(in + i + 4);
  u16x8 r;
  r[0] = f2bf(a[0]); r[1] = f2bf(a[1]); r[2] = f2bf(a[2]); r[3] = f2bf(a[3]);
  r[4] = f2bf(b[0]); r[5] = f2bf(b[1]); r[6] = f2bf(b[2]); r[7] = f2bf(b[3]);
  *reinterpret_cast<u16x8*>(out + z * ostride + i) = r;
}

// ---------------------------------------------------------------- bf16 transpose
// in: [4][2048][1024]  -> out: [4][1024][2048]
__global__ __launch_bounds__(256) void transpose_bf16k(const u16* __restrict__ in,
                                                       u16* __restrict__ out) {
  __shared__ u16 t[64][65];
  int c0 = blockIdx.x * 64, r0 = blockIdx.y * 64;
  size_t zb = (size_t)blockIdx.z * 2048 * 1024;
  const u16* I = in + zb;
  u16* O = out + zb;
  int tx = threadIdx.x & 63, ty = threadIdx.x >> 6;
  #pragma unroll
  for (int i = 0; i < 64; i += 4)
    t[ty + i][tx] = I[(size_t)(r0 + ty + i) * 1024 + c0 + tx];
  __syncthreads();
  #pragma unroll
  for (int i = 0; i < 64; i += 4)
    O[(size_t)(c0 + ty + i) * 2048 + r0 + tx] = t[tx][ty + i];
}

// ================================================================ fused-cast projection GEMM
// C[which] = (f32 A[which]) . (bf16 W[which])^T, A staged f32 in LDS with XOR-
// 16B-slot swizzle (pre-swizzled global col on stage, swizzled slot on read),
// converted to bf16 in-register after ds_read. 128x128 tile, BK=32, 2-phase dbuf.
// Grid 1536 flat, XCD-chunked; bm192: 0-63 -> Q, 64-127 -> K, 128-191 -> V.
__global__ __launch_bounds__(256) void proj_fused(
    const float* __restrict__ Aq, const float* __restrict__ Ak,
    const float* __restrict__ Av, const u16* __restrict__ W,
    u16* __restrict__ Qp, u16* __restrict__ Kp, u16* __restrict__ Vp) {
  int h = blockIdx.x;
  int l = (h & 7) * 192 + (h >> 3);    // bijective XCD chunking
  int bn = l & 7;
  int bm192 = l >> 3;
  int which = bm192 >> 6;
  int bm = bm192 & 63;
  const float* Ag = ((which == 0) ? Aq : (which == 1) ? Ak : Av) +
                    (size_t)bm * 128 * 1024;
  const u16* Bg = W + (size_t)which * 1048576 + (size_t)bn * 128 * 1024;
  u16* Cg = (which == 0) ? Qp : (which == 1) ? Kp : Vp;

  __shared__ __align__(16) float Af[2][128 * 32];  // 2 x 16KB
  __shared__ __align__(16) u16  Bs[2][128 * 32];   // 2 x 8KB

  const int tid = threadIdx.x, lane = tid & 63, wave = tid >> 6;
  const int wr = wave >> 1, wc = wave & 1;
  const int fr = lane & 15, hi = lane >> 4;

  // A staging: 16 chunks of 1KB (8 rows x 32 f32) per buffer; wave owns
  // chunks {wave, wave+4, wave+8, wave+12}. Lane l -> row 8c+(l>>3),
  // 16B slot (l&7); global col pre-swizzled so LDS slot s holds cols (s^(row&7))*4.
  const int arl = lane >> 3;                   // row within chunk (== row&7)
  const int acol = ((lane & 7) ^ arl) * 4;     // pre-swizzled f32 col
  const float* ag[4];
  int alds[4];
  #pragma unroll
  for (int j = 0; j < 4; ++j) {
    int c = wave + j * 4;
    ag[j] = Ag + (size_t)(c * 8 + arl) * 1024 + acol;
    alds[j] = c * 256;                         // float idx of chunk base
  }
  // B staging: 8 chunks of 1KB (16 rows x 32 bf16); wave owns {wave, wave+4}
  const int ch0 = wave, ch1 = wave + 4;
  const int e0 = ch0 * 512 + lane * 8, e1 = ch1 * 512 + lane * 8;
  const int br0 = e0 >> 5, bc0 = e0 & 31, br1 = e1 >> 5, bc1 = e1 & 31;
  const u16* b0 = Bg + (size_t)br0 * 1024 + bc0;
  const u16* b1 = Bg + (size_t)br1 * 1024 + bc1;

  f32x4 acc[4][4] = {};
  const int kq = hi * 8;

  // prologue: stage tile 0 into buffer 0
  #pragma unroll
  for (int j = 0; j < 4; ++j) gload16(ag[j], &Af[0][alds[j]]);
  gload16(b0, &Bs[0][ch0 * 512]);
  gload16(b1, &Bs[0][ch1 * 512]);
  __syncthreads();

  for (int t = 0; t < 32; ++t) {
    const int cur = t & 1;
    if (t + 1 < 32) {
      const int k0 = (t + 1) * 32;
      #pragma unroll
      for (int j = 0; j < 4; ++j) gload16(ag[j] + k0, &Af[cur ^ 1][alds[j]]);
      gload16(b0 + k0, &Bs[cur ^ 1][ch0 * 512]);
      gload16(b1 + k0, &Bs[cur ^ 1][ch1 * 512]);
    }
    bf16x8 af[4], bfv[4];
    #pragma unroll
    for (int m = 0; m < 4; ++m) {
      int r = wr * 64 + m * 16 + fr;
      int s0 = (hi * 2) ^ (r & 7);             // slot holding k=kq..kq+3
      f4v lo = *(const f4v*)&Af[cur][r * 32 + s0 * 4];
      f4v hh = *(const f4v*)&Af[cur][r * 32 + (s0 ^ 1) * 4];
      bf16x8 x;
      x[0] = (__bf16)lo[0]; x[1] = (__bf16)lo[1];
      x[2] = (__bf16)lo[2]; x[3] = (__bf16)lo[3];
      x[4] = (__bf16)hh[0]; x[5] = (__bf16)hh[1];
      x[6] = (__bf16)hh[2]; x[7] = (__bf16)hh[3];
      af[m] = x;
    }
    #pragma unroll
    for (int n = 0; n < 4; ++n)
      bfv[n] = *reinterpret_cast<const bf16x8*>(&Bs[cur][(wc * 64 + n * 16 + fr) * 32 + kq]);
    #pragma unroll
    for (int m = 0; m < 4; ++m)
      #pragma unroll
      for (int n = 0; n < 4; ++n)
        acc[m][n] = MF(af[m], bfv[n], acc[m][n]);
    __syncthreads();
  }

  const int row0 = bm * 128 + wr * 64 + hi * 4;
  const int col0 = bn * 128 + wc * 64 + fr;
  #pragma unroll
  for (int m = 0; m < 4; ++m)
    #pragma unroll
    for (int n = 0; n < 4; ++n)
      #pragma unroll
      for (int j = 0; j < 4; ++j)
        Cg[(size_t)(row0 + m * 16 + j) * 1024 + (col0 + n * 16)] = f2bf(acc[m][n][j]);
}

// ---------------------------------------------------------------- GEMM  C = alpha * A . B^T
// MODE 1: causal QK^T, triangular-packed lower-tri tiles, XCD-swizzled.
// MODE 2: causal PV, K clipped to (bm+1)*BM, longest-blocks-first, no swizzle.
#define BM 128
#define BN 128
#define BK 32

template<typename OutT, int MODE>
__global__ __launch_bounds__(256) void gemm_bt(
    const u16* __restrict__ A, const u16* __restrict__ B, OutT* __restrict__ C,
    int K, int lda, int ldb, int ldc,
    size_t sA, size_t sB, size_t sC, float alpha) {
  int bn, bm, bz;
  int kEnd = K;
  if (MODE == 1) {                       // grid 544 = 4 * 136 lower-tri tiles
    int h = blockIdx.x;
    int l = (h & 7) * 68 + (h >> 3);
    bz = l / 136;
    int t = l % 136;
    bm = (int)((sqrtf(8.f * (float)t + 1.f) - 1.f) * 0.5f);
    while ((bm + 1) * (bm + 2) / 2 <= t) ++bm;
    while (bm * (bm + 1) / 2 > t) --bm;
    bn = t - bm * (bm + 1) / 2;
  } else {                               // MODE 2, grid 512
    int l = blockIdx.x;
    bm = 15 - (l >> 5);                  // longest kEnd first
    int rest = l & 31;
    bz = rest >> 3;
    bn = rest & 7;
    kEnd = (K < (bm + 1) * BM) ? K : (bm + 1) * BM;
  }
  const u16* Ag = A + sA * bz + (size_t)bm * BM * lda;
  const u16* Bg = B + sB * bz + (size_t)bn * BN * ldb;
  OutT* Cg = C + sC * bz;

  __shared__ __align__(16) u16 As[2][BM * BK];
  __shared__ __align__(16) u16 Bs[2][BN * BK];

  const int tid = threadIdx.x;
  const int lane = tid & 63, wave = tid >> 6;
  const int wr = wave >> 1, wc = wave & 1;

  const int ch0 = wave, ch1 = wave + 4;
  const int e0 = ch0 * 512 + lane * 8, e1 = ch1 * 512 + lane * 8;
  const int r0 = e0 >> 5, c0 = e0 & 31, r1 = e1 >> 5, c1 = e1 & 31;
  const u16* a0 = Ag + (size_t)r0 * lda + c0;
  const u16* a1 = Ag + (size_t)r1 * lda + c1;
  const u16* b0 = Bg + (size_t)r0 * ldb + c0;
  const u16* b1 = Bg + (size_t)r1 * ldb + c1;

  f32x4 acc[4][4] = {};

  const int fr = lane & 15, kq = (lane >> 4) * 8;
  const int nt = kEnd / BK;

  gload16(a0, &As[0][ch0 * 512]);
  gload16(a1, &As[0][ch1 * 512]);
  gload16(b0, &Bs[0][ch0 * 512]);
  gload16(b1, &Bs[0][ch1 * 512]);
  __syncthreads();

  for (int t = 0; t < nt; ++t) {
    const int cur = t & 1;
    if (t + 1 < nt) {
      const int k0 = (t + 1) * BK;
      gload16(a0 + k0, &As[cur ^ 1][ch0 * 512]);
      gload16(a1 + k0, &As[cur ^ 1][ch1 * 512]);
      gload16(b0 + k0, &Bs[cur ^ 1][ch0 * 512]);
      gload16(b1 + k0, &Bs[cur ^ 1][ch1 * 512]);
    }
    bf16x8 af[4], bfv[4];
    #pragma unroll
    for (int m = 0; m < 4; ++m)
      af[m] = *reinterpret_cast<const bf16x8*>(&As[cur][(wr * 64 + m * 16 + fr) * BK + kq]);
    #pragma unroll
    for (int n = 0; n < 4; ++n)
      bfv[n] = *reinterpret_cast<const bf16x8*>(&Bs[cur][(wc * 64 + n * 16 + fr) * BK + kq]);
    #pragma unroll
    for (int m = 0; m < 4; ++m)
      #pragma unroll
      for (int n = 0; n < 4; ++n)
        acc[m][n] = MF(af[m], bfv[n], acc[m][n]);
    __syncthreads();
  }

  const int row0 = bm * BM + wr * 64 + (lane >> 4) * 4;
  const int col0 = bn * BN + wc * 64 + fr;
  #pragma unroll
  for (int m = 0; m < 4; ++m)
    #pragma unroll
    for (int n = 0; n < 4; ++n) {
      #pragma unroll
      for (int j = 0; j < 4; ++j) {
        float val = acc[m][n][j] * alpha;
        size_t idx = (size_t)(row0 + m * 16 + j) * ldc + (col0 + n * 16);
        if constexpr (sizeof(OutT) == 2) Cg[idx] = f2bf(val);
        else Cg[idx] = val;
      }
    }
}

// ---------------------------------------------------------------- causal softmax (in-place)
// scores: [4][2048][2048] f32. Row r: softmax over t<=s, bf16 P written into the
// same row slot (ldp = 4096 u16). Causal-aware loads/stores.
__global__ __launch_bounds__(256) void softmax_causal(float* __restrict__ sc) {
  int r = blockIdx.x;          // 0..8191
  int s = r & 2047;
  float* row = sc + (size_t)r * 2048;
  int tid = threadIdx.x;
  int t0 = tid * 8;
  f4v x0 = {-1e30f, -1e30f, -1e30f, -1e30f};
  f4v x1 = {-1e30f, -1e30f, -1e30f, -1e30f};
  if (t0 <= s)     x0 = reinterpret_cast<const f4v*>(row)[tid * 2];
  if (t0 + 4 <= s) x1 = reinterpret_cast<const f4v*>(row)[tid * 2 + 1];
  float v[8] = {x0[0], x0[1], x0[2], x0[3], x1[0], x1[1], x1[2], x1[3]};
  float mx = -1e30f;
  #pragma unroll
  for (int j = 0; j < 8; ++j) {
    v[j] = ((t0 + j) <= s) ? v[j] : -1e30f;
    mx = fmaxf(mx, v[j]);
  }
  #pragma unroll
  for (int o = 32; o; o >>= 1) mx = fmaxf(mx, __shfl_xor(mx, o, 64));
  __shared__ float red[8];
  if ((tid & 63) == 0) red[tid >> 6] = mx;
  __syncthreads();
  mx = fmaxf(fmaxf(red[0], red[1]), fmaxf(red[2], red[3]));
  float p[8];
  float sum = 0.f;
  #pragma unroll
  for (int j = 0; j < 8; ++j) {
    p[j] = ((t0 + j) <= s) ? __expf(v[j] - mx) : 0.f;
    sum += p[j];
  }
  #pragma unroll
  for (int o = 32; o; o >>= 1) sum += __shfl_xor(sum, o, 64);
  if ((tid & 63) == 0) red[4 + (tid >> 6)] = sum;
  __syncthreads();
  sum = red[4] + red[5] + red[6] + red[7];
  float inv = 1.0f / sum;
  u16x8 o8;
  #pragma unroll
  for (int j = 0; j < 8; ++j) o8[j] = f2bf(p[j] * inv);
  if (t0 <= (s | 127))   // PV reads cols < (bm+1)*128 only
    reinterpret_cast<u16x8*>(row)[tid] = o8;
}

// ---------------------------------------------------------------- launcher
extern "C" void kernel_launch(void* const* d_in, const int* in_sizes, int n_in,
                              void* d_out, int out_size, void* d_ws, size_t ws_size,
                              hipStream_t stream) {
  const float* q  = (const float*)d_in[0];
  const float* k  = (const float*)d_in[1];
  const float* v  = (const float*)d_in[2];
  // d_in[3] = attn_mask (causal tril) — handled analytically
  const float* Wq = (const float*)d_in[4];
  const float* Wk = (const float*)d_in[5];
  const float* Wv = (const float*)d_in[6];
  float* out = (float*)d_out;
  char* ws = (char*)d_ws;

  const size_t MB = 1024ull * 1024ull;
  // Liveness: Vp & wqb die before sc is written (QK); sc overlays them.
  float* sc = (float*)ws;            // 0..64MB
  u16* Vp  = (u16*)(ws + 0 * MB);    // 16MB (dead after transpose)
  u16* wqb = (u16*)(ws + 16 * MB);   // 6MB  (dead after proj)
  u16* Vt  = (u16*)(ws + 64 * MB);   // 16MB
  u16* Kp  = (u16*)(ws + 80 * MB);   // 16MB
  u16* Qp  = (u16*)(ws + 96 * MB);   // 16MB  -> peak 112MB
  (void)in_sizes; (void)n_in; (void)out_size; (void)ws_size;

  // 1. cast weights only (Q/K/V cast is fused into the projection)
  cast3_f32_bf16<<<dim3(512, 1, 3), 256, 0, stream>>>(Wq, Wk, Wv, wqb, 1048576);

  // 2. fused-cast projections (1536 blocks, XCD-swizzled)
  proj_fused<<<1536, 256, 0, stream>>>(q, k, v, wqb, Qp, Kp, Vp);

  // 3. V transpose -> Vt[4][1024][2048]
  transpose_bf16k<<<dim3(16, 32, 4), 256, 0, stream>>>(Vp, Vt);

  // 4. QK^T (scaled, triangular-packed, XCD-swizzled) -> scores f32
  gemm_bt<float, 1><<<544, 256, 0, stream>>>(
      Qp, Kp, sc, 1024, 1024, 1024, 2048,
      (size_t)2048 * 1024, (size_t)2048 * 1024, (size_t)2048 * 2048, 0.03125f);

  // 5. causal softmax, bf16 P written in place (ldp = 4096 u16)
  softmax_causal<<<8192, 256, 0, stream>>>(sc);

  // 6. PV: P[2048][2048](lda 4096) . Vt[1024][2048]^T -> out f32, longest-first
  gemm_bt<float, 2><<<512, 256, 0, stream>>>(
      (u16*)ws, Vt, out, 2048, 4096, 2048, 1024,
      (size_t)2048 * 4096, (size_t)1024 * 2048, (size_t)2048 * 1024, 1.0f);
}

// Round 6
// 185.976 us; speedup vs baseline: 1.2757x; 1.2757x over previous
//
#include <hip/hip_runtime.h>
#include <math.h>

using u16 = unsigned short;
typedef __attribute__((ext_vector_type(8))) __bf16 bf16x8;
typedef __attribute__((ext_vector_type(4))) float f32x4;
typedef __attribute__((ext_vector_type(4))) float f4v;
typedef __attribute__((ext_vector_type(8))) u16 u16x8;

__device__ __forceinline__ u16 f2bf(float f) {
  unsigned u = __float_as_uint(f);
  u += 0x7fffu + ((u >> 16) & 1u);   // round-to-nearest-even
  return (u16)(u >> 16);
}

__device__ __forceinline__ void gload16(const void* g, void* l) {
  __builtin_amdgcn_global_load_lds(
      (const __attribute__((address_space(1))) unsigned int*)g,
      (__attribute__((address_space(3))) unsigned int*)l, 16, 0, 0);
}

__device__ __forceinline__ f32x4 MF(bf16x8 a, bf16x8 b, f32x4 c) {
  return __builtin_amdgcn_mfma_f32_16x16x32_bf16(a, b, c, 0, 0, 0);
}

// ---------------------------------------------------------------- cast f32->bf16 (weights only)
__global__ __launch_bounds__(256) void cast3_f32_bf16(
    const float* __restrict__ p0, const float* __restrict__ p1,
    const float* __restrict__ p2, u16* __restrict__ out, size_t ostride) {
  int z = blockIdx.z;
  const float* in = (z == 0) ? p0 : (z == 1) ? p1 : p2;
  size_t i = ((size_t)blockIdx.x * 256 + threadIdx.x) * 8;
  f4v a = *reinterpret_cast<const f4v*>(in + i);
  f4v b = *reinterpret_cast<const f4v*>(in + i + 4);
  u16x8 r;
  r[0] = f2bf(a[0]); r[1] = f2bf(a[1]); r[2] = f2bf(a[2]); r[3] = f2bf(a[3]);
  r[4] = f2bf(b[0]); r[5] = f2bf(b[1]); r[6] = f2bf(b[2]); r[7] = f2bf(b[3]);
  *reinterpret_cast<u16x8*>(out + z * ostride + i) = r;
}

// ---------------------------------------------------------------- bf16 transpose
// in: [4][2048][1024]  -> out: [4][1024][2048]
__global__ __launch_bounds__(256) void transpose_bf16k(const u16* __restrict__ in,
                                                       u16* __restrict__ out) {
  __shared__ u16 t[64][65];
  int c0 = blockIdx.x * 64, r0 = blockIdx.y * 64;
  size_t zb = (size_t)blockIdx.z * 2048 * 1024;
  const u16* I = in + zb;
  u16* O = out + zb;
  int tx = threadIdx.x & 63, ty = threadIdx.x >> 6;
  #pragma unroll
  for (int i = 0; i < 64; i += 4)
    t[ty + i][tx] = I[(size_t)(r0 + ty + i) * 1024 + c0 + tx];
  __syncthreads();
  #pragma unroll
  for (int i = 0; i < 64; i += 4)
    O[(size_t)(c0 + ty + i) * 2048 + r0 + tx] = t[tx][ty + i];
}

// ================================================================ fused-cast projection GEMM
// C[which] = (f32 A[which]) . (bf16 W[which])^T. A is reg-staged: f32 global
// loads -> registers (issued before the MFMA phase) -> bf16 cvt -> ds_write
// into the *other* LDS buffer (its readers finished before the last barrier).
// Inner loop (LDS layout, ds_reads, MFMA) identical to the proven 2-phase
// bf16 kernel; LDS stays 32 KB. B (weights) staged via global_load_lds.
// Grid 1536 flat, XCD-chunked; bm192: 0-63 -> Q, 64-127 -> K, 128-191 -> V.
__global__ __launch_bounds__(256) void proj_fused(
    const float* __restrict__ Aq, const float* __restrict__ Ak,
    const float* __restrict__ Av, const u16* __restrict__ W,
    u16* __restrict__ Qp, u16* __restrict__ Kp, u16* __restrict__ Vp) {
  int h = blockIdx.x;
  int l = (h & 7) * 192 + (h >> 3);    // bijective XCD chunking
  int bn = l & 7;
  int bm192 = l >> 3;
  int which = bm192 >> 6;
  int bm = bm192 & 63;
  const float* Ag = ((which == 0) ? Aq : (which == 1) ? Ak : Av) +
                    (size_t)bm * 128 * 1024;
  const u16* Bg = W + (size_t)which * 1048576 + (size_t)bn * 128 * 1024;
  u16* Cg = (which == 0) ? Qp : (which == 1) ? Kp : Vp;

  __shared__ __align__(16) u16 As[2][128 * 32];   // 2 x 8KB
  __shared__ __align__(16) u16 Bs[2][128 * 32];   // 2 x 8KB

  const int tid = threadIdx.x, lane = tid & 63, wave = tid >> 6;
  const int wr = wave >> 1, wc = wave & 1;
  const int fr = lane & 15, kq = (lane >> 4) * 8;

  // A reg-staging: thread -> row tid>>1, col (tid&1)*16 (16 f32 = 4 dwordx4)
  const int arow = tid >> 1, acol = (tid & 1) * 16;
  const float* ags = Ag + (size_t)arow * 1024 + acol;
  // B staging via gload16: 8 chunks of 1KB; wave owns {wave, wave+4}
  const int ch0 = wave, ch1 = wave + 4;
  const int e0 = ch0 * 512 + lane * 8, e1 = ch1 * 512 + lane * 8;
  const int br0 = e0 >> 5, bc0 = e0 & 31, br1 = e1 >> 5, bc1 = e1 & 31;
  const u16* b0 = Bg + (size_t)br0 * 1024 + bc0;
  const u16* b1 = Bg + (size_t)br1 * 1024 + bc1;

  f32x4 acc[4][4] = {};

  // prologue: tile 0 -> buffer 0
  {
    f4v p0 = *(const f4v*)(ags);
    f4v p1 = *(const f4v*)(ags + 4);
    f4v p2 = *(const f4v*)(ags + 8);
    f4v p3 = *(const f4v*)(ags + 12);
    gload16(b0, &Bs[0][ch0 * 512]);
    gload16(b1, &Bs[0][ch1 * 512]);
    bf16x8 w0, w1;
    w0[0] = (__bf16)p0[0]; w0[1] = (__bf16)p0[1]; w0[2] = (__bf16)p0[2]; w0[3] = (__bf16)p0[3];
    w0[4] = (__bf16)p1[0]; w0[5] = (__bf16)p1[1]; w0[6] = (__bf16)p1[2]; w0[7] = (__bf16)p1[3];
    w1[0] = (__bf16)p2[0]; w1[1] = (__bf16)p2[1]; w1[2] = (__bf16)p2[2]; w1[3] = (__bf16)p2[3];
    w1[4] = (__bf16)p3[0]; w1[5] = (__bf16)p3[1]; w1[6] = (__bf16)p3[2]; w1[7] = (__bf16)p3[3];
    *(bf16x8*)&As[0][arow * 32 + acol] = w0;
    *(bf16x8*)&As[0][arow * 32 + acol + 8] = w1;
  }
  __syncthreads();

  for (int t = 0; t < 32; ++t) {
    const int cur = t & 1;
    f4v p0, p1, p2, p3;
    if (t + 1 < 32) {
      const float* ap = ags + (t + 1) * 32;
      p0 = *(const f4v*)(ap);          // issued早 -> latency hides under MFMA
      p1 = *(const f4v*)(ap + 4);
      p2 = *(const f4v*)(ap + 8);
      p3 = *(const f4v*)(ap + 12);
      const int k0 = (t + 1) * 32;
      gload16(b0 + k0, &Bs[cur ^ 1][ch0 * 512]);
      gload16(b1 + k0, &Bs[cur ^ 1][ch1 * 512]);
    }
    bf16x8 af[4], bfv[4];
    #pragma unroll
    for (int m = 0; m < 4; ++m)
      af[m] = *reinterpret_cast<const bf16x8*>(&As[cur][(wr * 64 + m * 16 + fr) * 32 + kq]);
    #pragma unroll
    for (int n = 0; n < 4; ++n)
      bfv[n] = *reinterpret_cast<const bf16x8*>(&Bs[cur][(wc * 64 + n * 16 + fr) * 32 + kq]);
    #pragma unroll
    for (int m = 0; m < 4; ++m)
      #pragma unroll
      for (int n = 0; n < 4; ++n)
        acc[m][n] = MF(af[m], bfv[n], acc[m][n]);
    if (t + 1 < 32) {                  // cvt + ds_write into the other buffer
      bf16x8 w0, w1;
      w0[0] = (__bf16)p0[0]; w0[1] = (__bf16)p0[1]; w0[2] = (__bf16)p0[2]; w0[3] = (__bf16)p0[3];
      w0[4] = (__bf16)p1[0]; w0[5] = (__bf16)p1[1]; w0[6] = (__bf16)p1[2]; w0[7] = (__bf16)p1[3];
      w1[0] = (__bf16)p2[0]; w1[1] = (__bf16)p2[1]; w1[2] = (__bf16)p2[2]; w1[3] = (__bf16)p2[3];
      w1[4] = (__bf16)p3[0]; w1[5] = (__bf16)p3[1]; w1[6] = (__bf16)p3[2]; w1[7] = (__bf16)p3[3];
      *(bf16x8*)&As[cur ^ 1][arow * 32 + acol] = w0;
      *(bf16x8*)&As[cur ^ 1][arow * 32 + acol + 8] = w1;
    }
    __syncthreads();
  }

  const int row0 = bm * 128 + wr * 64 + (lane >> 4) * 4;
  const int col0 = bn * 128 + wc * 64 + fr;
  #pragma unroll
  for (int m = 0; m < 4; ++m)
    #pragma unroll
    for (int n = 0; n < 4; ++n)
      #pragma unroll
      for (int j = 0; j < 4; ++j)
        Cg[(size_t)(row0 + m * 16 + j) * 1024 + (col0 + n * 16)] = f2bf(acc[m][n][j]);
}

// ---------------------------------------------------------------- GEMM  C = alpha * A . B^T
// MODE 1: causal QK^T, triangular-packed lower-tri tiles, XCD-swizzled.
// MODE 2: causal PV, K clipped to (bm+1)*BM, longest-blocks-first, no swizzle.
#define BM 128
#define BN 128
#define BK 32

template<typename OutT, int MODE>
__global__ __launch_bounds__(256) void gemm_bt(
    const u16* __restrict__ A, const u16* __restrict__ B, OutT* __restrict__ C,
    int K, int lda, int ldb, int ldc,
    size_t sA, size_t sB, size_t sC, float alpha) {
  int bn, bm, bz;
  int kEnd = K;
  if (MODE == 1) {                       // grid 544 = 4 * 136 lower-tri tiles
    int h = blockIdx.x;
    int l = (h & 7) * 68 + (h >> 3);
    bz = l / 136;
    int t = l % 136;
    bm = (int)((sqrtf(8.f * (float)t + 1.f) - 1.f) * 0.5f);
    while ((bm + 1) * (bm + 2) / 2 <= t) ++bm;
    while (bm * (bm + 1) / 2 > t) --bm;
    bn = t - bm * (bm + 1) / 2;
  } else {                               // MODE 2, grid 512
    int l = blockIdx.x;
    bm = 15 - (l >> 5);                  // longest kEnd first
    int rest = l & 31;
    bz = rest >> 3;
    bn = rest & 7;
    kEnd = (K < (bm + 1) * BM) ? K : (bm + 1) * BM;
  }
  const u16* Ag = A + sA * bz + (size_t)bm * BM * lda;
  const u16* Bg = B + sB * bz + (size_t)bn * BN * ldb;
  OutT* Cg = C + sC * bz;

  __shared__ __align__(16) u16 As[2][BM * BK];
  __shared__ __align__(16) u16 Bs[2][BN * BK];

  const int tid = threadIdx.x;
  const int lane = tid & 63, wave = tid >> 6;
  const int wr = wave >> 1, wc = wave & 1;

  const int ch0 = wave, ch1 = wave + 4;
  const int e0 = ch0 * 512 + lane * 8, e1 = ch1 * 512 + lane * 8;
  const int r0 = e0 >> 5, c0 = e0 & 31, r1 = e1 >> 5, c1 = e1 & 31;
  const u16* a0 = Ag + (size_t)r0 * lda + c0;
  const u16* a1 = Ag + (size_t)r1 * lda + c1;
  const u16* b0 = Bg + (size_t)r0 * ldb + c0;
  const u16* b1 = Bg + (size_t)r1 * ldb + c1;

  f32x4 acc[4][4] = {};

  const int fr = lane & 15, kq = (lane >> 4) * 8;
  const int nt = kEnd / BK;

  gload16(a0, &As[0][ch0 * 512]);
  gload16(a1, &As[0][ch1 * 512]);
  gload16(b0, &Bs[0][ch0 * 512]);
  gload16(b1, &Bs[0][ch1 * 512]);
  __syncthreads();

  for (int t = 0; t < nt; ++t) {
    const int cur = t & 1;
    if (t + 1 < nt) {
      const int k0 = (t + 1) * BK;
      gload16(a0 + k0, &As[cur ^ 1][ch0 * 512]);
      gload16(a1 + k0, &As[cur ^ 1][ch1 * 512]);
      gload16(b0 + k0, &Bs[cur ^ 1][ch0 * 512]);
      gload16(b1 + k0, &Bs[cur ^ 1][ch1 * 512]);
    }
    bf16x8 af[4], bfv[4];
    #pragma unroll
    for (int m = 0; m < 4; ++m)
      af[m] = *reinterpret_cast<const bf16x8*>(&As[cur][(wr * 64 + m * 16 + fr) * BK + kq]);
    #pragma unroll
    for (int n = 0; n < 4; ++n)
      bfv[n] = *reinterpret_cast<const bf16x8*>(&Bs[cur][(wc * 64 + n * 16 + fr) * BK + kq]);
    #pragma unroll
    for (int m = 0; m < 4; ++m)
      #pragma unroll
      for (int n = 0; n < 4; ++n)
        acc[m][n] = MF(af[m], bfv[n], acc[m][n]);
    __syncthreads();
  }

  const int row0 = bm * BM + wr * 64 + (lane >> 4) * 4;
  const int col0 = bn * BN + wc * 64 + fr;
  #pragma unroll
  for (int m = 0; m < 4; ++m)
    #pragma unroll
    for (int n = 0; n < 4; ++n) {
      #pragma unroll
      for (int j = 0; j < 4; ++j) {
        float val = acc[m][n][j] * alpha;
        size_t idx = (size_t)(row0 + m * 16 + j) * ldc + (col0 + n * 16);
        if constexpr (sizeof(OutT) == 2) Cg[idx] = f2bf(val);
        else Cg[idx] = val;
      }
    }
}

// ---------------------------------------------------------------- causal softmax (in-place)
// scores: [4][2048][2048] f32. Row r: softmax over t<=s, bf16 P written into the
// same row slot (ldp = 4096 u16). Causal-aware loads/stores.
__global__ __launch_bounds__(256) void softmax_causal(float* __restrict__ sc) {
  int r = blockIdx.x;          // 0..8191
  int s = r & 2047;
  float* row = sc + (size_t)r * 2048;
  int tid = threadIdx.x;
  int t0 = tid * 8;
  f4v x0 = {-1e30f, -1e30f, -1e30f, -1e30f};
  f4v x1 = {-1e30f, -1e30f, -1e30f, -1e30f};
  if (t0 <= s)     x0 = reinterpret_cast<const f4v*>(row)[tid * 2];
  if (t0 + 4 <= s) x1 = reinterpret_cast<const f4v*>(row)[tid * 2 + 1];
  float v[8] = {x0[0], x0[1], x0[2], x0[3], x1[0], x1[1], x1[2], x1[3]};
  float mx = -1e30f;
  #pragma unroll
  for (int j = 0; j < 8; ++j) {
    v[j] = ((t0 + j) <= s) ? v[j] : -1e30f;
    mx = fmaxf(mx, v[j]);
  }
  #pragma unroll
  for (int o = 32; o; o >>= 1) mx = fmaxf(mx, __shfl_xor(mx, o, 64));
  __shared__ float red[8];
  if ((tid & 63) == 0) red[tid >> 6] = mx;
  __syncthreads();
  mx = fmaxf(fmaxf(red[0], red[1]), fmaxf(red[2], red[3]));
  float p[8];
  float sum = 0.f;
  #pragma unroll
  for (int j = 0; j < 8; ++j) {
    p[j] = ((t0 + j) <= s) ? __expf(v[j] - mx) : 0.f;
    sum += p[j];
  }
  #pragma unroll
  for (int o = 32; o; o >>= 1) sum += __shfl_xor(sum, o, 64);
  if ((tid & 63) == 0) red[4 + (tid >> 6)] = sum;
  __syncthreads();
  sum = red[4] + red[5] + red[6] + red[7];
  float inv = 1.0f / sum;
  u16x8 o8;
  #pragma unroll
  for (int j = 0; j < 8; ++j) o8[j] = f2bf(p[j] * inv);
  if (t0 <= (s | 127))   // PV reads cols < (bm+1)*128 only
    reinterpret_cast<u16x8*>(row)[tid] = o8;
}

// ---------------------------------------------------------------- launcher
extern "C" void kernel_launch(void* const* d_in, const int* in_sizes, int n_in,
                              void* d_out, int out_size, void* d_ws, size_t ws_size,
                              hipStream_t stream) {
  const float* q  = (const float*)d_in[0];
  const float* k  = (const float*)d_in[1];
  const float* v  = (const float*)d_in[2];
  // d_in[3] = attn_mask (causal tril) — handled analytically
  const float* Wq = (const float*)d_in[4];
  const float* Wk = (const float*)d_in[5];
  const float* Wv = (const float*)d_in[6];
  float* out = (float*)d_out;
  char* ws = (char*)d_ws;

  const size_t MB = 1024ull * 1024ull;
  // Liveness: Vp & wqb die before sc is written (QK); sc overlays them.
  float* sc = (float*)ws;            // 0..64MB
  u16* Vp  = (u16*)(ws + 0 * MB);    // 16MB (dead after transpose)
  u16* wqb = (u16*)(ws + 16 * MB);   // 6MB  (dead after proj)
  u16* Vt  = (u16*)(ws + 64 * MB);   // 16MB
  u16* Kp  = (u16*)(ws + 80 * MB);   // 16MB
  u16* Qp  = (u16*)(ws + 96 * MB);   // 16MB  -> peak 112MB
  (void)in_sizes; (void)n_in; (void)out_size; (void)ws_size;

  // 1. cast weights only (Q/K/V input cast is fused into the projection)
  cast3_f32_bf16<<<dim3(512, 1, 3), 256, 0, stream>>>(Wq, Wk, Wv, wqb, 1048576);

  // 2. fused-cast projections (1536 blocks, XCD-swizzled, reg-staged f32 A)
  proj_fused<<<1536, 256, 0, stream>>>(q, k, v, wqb, Qp, Kp, Vp);

  // 3. V transpose -> Vt[4][1024][2048]
  transpose_bf16k<<<dim3(16, 32, 4), 256, 0, stream>>>(Vp, Vt);

  // 4. QK^T (scaled, triangular-packed, XCD-swizzled) -> scores f32
  gemm_bt<float, 1><<<544, 256, 0, stream>>>(
      Qp, Kp, sc, 1024, 1024, 1024, 2048,
      (size_t)2048 * 1024, (size_t)2048 * 1024, (size_t)2048 * 2048, 0.03125f);

  // 5. causal softmax, bf16 P written in place (ldp = 4096 u16)
  softmax_causal<<<8192, 256, 0, stream>>>(sc);

  // 6. PV: P[2048][2048](lda 4096) . Vt[1024][2048]^T -> out f32, longest-first
  gemm_bt<float, 2><<<512, 256, 0, stream>>>(
      (u16*)ws, Vt, out, 2048, 4096, 2048, 1024,
      (size_t)2048 * 4096, (size_t)1024 * 2048, (size_t)2048 * 1024, 1.0f);
}

// Round 7
// 180.741 us; speedup vs baseline: 1.3126x; 1.0290x over previous
//
#include <hip/hip_runtime.h>
#include <math.h>

using u16 = unsigned short;
typedef __attribute__((ext_vector_type(8))) __bf16 bf16x8;
typedef __attribute__((ext_vector_type(4))) float f32x4;
typedef __attribute__((ext_vector_type(4))) float f4v;
typedef __attribute__((ext_vector_type(8))) u16 u16x8;

__device__ __forceinline__ u16 f2bf(float f) {
  unsigned u = __float_as_uint(f);
  u += 0x7fffu + ((u >> 16) & 1u);   // round-to-nearest-even
  return (u16)(u >> 16);
}

__device__ __forceinline__ void gload16(const void* g, void* l) {
  __builtin_amdgcn_global_load_lds(
      (const __attribute__((address_space(1))) unsigned int*)g,
      (__attribute__((address_space(3))) unsigned int*)l, 16, 0, 0);
}

__device__ __forceinline__ f32x4 MF(bf16x8 a, bf16x8 b, f32x4 c) {
  return __builtin_amdgcn_mfma_f32_16x16x32_bf16(a, b, c, 0, 0, 0);
}

__device__ __forceinline__ bf16x8 pk8(f4v a, f4v b) {
  bf16x8 x;
  x[0] = (__bf16)a[0]; x[1] = (__bf16)a[1]; x[2] = (__bf16)a[2]; x[3] = (__bf16)a[3];
  x[4] = (__bf16)b[0]; x[5] = (__bf16)b[1]; x[6] = (__bf16)b[2]; x[7] = (__bf16)b[3];
  return x;
}

// ---------------------------------------------------------------- cast f32->bf16 (weights only)
__global__ __launch_bounds__(256) void cast3_f32_bf16(
    const float* __restrict__ p0, const float* __restrict__ p1,
    const float* __restrict__ p2, u16* __restrict__ out, size_t ostride) {
  int z = blockIdx.z;
  const float* in = (z == 0) ? p0 : (z == 1) ? p1 : p2;
  size_t i = ((size_t)blockIdx.x * 256 + threadIdx.x) * 8;
  f4v a = *reinterpret_cast<const f4v*>(in + i);
  f4v b = *reinterpret_cast<const f4v*>(in + i + 4);
  u16x8 r;
  r[0] = f2bf(a[0]); r[1] = f2bf(a[1]); r[2] = f2bf(a[2]); r[3] = f2bf(a[3]);
  r[4] = f2bf(b[0]); r[5] = f2bf(b[1]); r[6] = f2bf(b[2]); r[7] = f2bf(b[3]);
  *reinterpret_cast<u16x8*>(out + z * ostride + i) = r;
}

// ---------------------------------------------------------------- bf16 transpose
// in: [4][2048][1024]  -> out: [4][1024][2048]
__global__ __launch_bounds__(256) void transpose_bf16k(const u16* __restrict__ in,
                                                       u16* __restrict__ out) {
  __shared__ u16 t[64][65];
  int c0 = blockIdx.x * 64, r0 = blockIdx.y * 64;
  size_t zb = (size_t)blockIdx.z * 2048 * 1024;
  const u16* I = in + zb;
  u16* O = out + zb;
  int tx = threadIdx.x & 63, ty = threadIdx.x >> 6;
  #pragma unroll
  for (int i = 0; i < 64; i += 4)
    t[ty + i][tx] = I[(size_t)(r0 + ty + i) * 1024 + c0 + tx];
  __syncthreads();
  #pragma unroll
  for (int i = 0; i < 64; i += 4)
    O[(size_t)(c0 + ty + i) * 2048 + r0 + tx] = t[tx][ty + i];
}

// ================================================================ fused-cast projection GEMM
// C[which] = (f32 A[which]) . (bf16 W[which])^T.
// Depth-2 A reg-staging: regs for tile t+2 loaded at iter t, cvt+ds_write at
// iter t+1 -> a full compute phase + barrier of latency hiding. Raw s_barrier
// with counted vmcnt(4): B gloads (issued FIRST = oldest) drained; the 4 t+2
// reg loads stay in flight across the barrier. ds_write lane->byte l*16:
// conflict-free. Consume path identical to the proven 2-phase bf16 kernel.
// Grid 1536 flat, XCD-chunked; bm192: 0-63 -> Q, 64-127 -> K, 128-191 -> V.
__global__ __launch_bounds__(256) void proj_fused(
    const float* __restrict__ Aq, const float* __restrict__ Ak,
    const float* __restrict__ Av, const u16* __restrict__ W,
    u16* __restrict__ Qp, u16* __restrict__ Kp, u16* __restrict__ Vp) {
  int h = blockIdx.x;
  int l = (h & 7) * 192 + (h >> 3);    // bijective XCD chunking
  int bn = l & 7;
  int bm192 = l >> 3;
  int which = bm192 >> 6;
  int bm = bm192 & 63;
  const float* Ag = ((which == 0) ? Aq : (which == 1) ? Ak : Av) +
                    (size_t)bm * 128 * 1024;
  const u16* Bg = W + (size_t)which * 1048576 + (size_t)bn * 128 * 1024;
  u16* Cg = (which == 0) ? Qp : (which == 1) ? Kp : Vp;

  __shared__ __align__(16) u16 As[2][128 * 32];   // 2 x 8KB
  __shared__ __align__(16) u16 Bs[2][128 * 32];   // 2 x 8KB

  const int tid = threadIdx.x, lane = tid & 63, wave = tid >> 6;
  const int wr = wave >> 1, wc = wave & 1;
  const int fr = lane & 15, kq = (lane >> 4) * 8;

  // A reg-staging map: thread -> rows {tid>>2, 64+(tid>>2)}, cols (tid&3)*8..+7
  // LDS write bytes: lane l -> l*16 (and +4KB) => conflict-free.
  const float* ag0 = Ag + (size_t)(tid >> 2) * 1024 + (tid & 3) * 8;
  const float* ag1 = ag0 + 64 * 1024;
  const int w0i = (tid >> 2) * 32 + (tid & 3) * 8;
  const int w1i = w0i + 2048;
  // B staging via gload16: 8 chunks of 1KB; wave owns {wave, wave+4}
  const int ch0 = wave, ch1 = wave + 4;
  const int e0 = ch0 * 512 + lane * 8, e1 = ch1 * 512 + lane * 8;
  const int br0 = e0 >> 5, bc0 = e0 & 31, br1 = e1 >> 5, bc1 = e1 & 31;
  const u16* b0 = Bg + (size_t)br0 * 1024 + bc0;
  const u16* b1 = Bg + (size_t)br1 * 1024 + bc1;

  f32x4 acc[4][4] = {};
  f4v pc0, pc1, pc2, pc3, pn0, pn1, pn2, pn3;

  // ---- prologue: B(0) gload (oldest), R(0), R(1); cvt R(0)->As[0]; barrier
  gload16(b0, &Bs[0][ch0 * 512]);
  gload16(b1, &Bs[0][ch1 * 512]);
  pc0 = *(const f4v*)(ag0);      pc1 = *(const f4v*)(ag0 + 4);
  pc2 = *(const f4v*)(ag1);      pc3 = *(const f4v*)(ag1 + 4);
  pn0 = *(const f4v*)(ag0 + 32); pn1 = *(const f4v*)(ag0 + 36);
  pn2 = *(const f4v*)(ag1 + 32); pn3 = *(const f4v*)(ag1 + 36);
  *(bf16x8*)&As[0][w0i] = pk8(pc0, pc1);   // compiler waits R(0) -> drains B(0) too
  *(bf16x8*)&As[0][w1i] = pk8(pc2, pc3);
  pc0 = pn0; pc1 = pn1; pc2 = pn2; pc3 = pn3;
  asm volatile("s_waitcnt vmcnt(4)" ::: "memory");   // only R(1) may remain
  asm volatile("s_waitcnt lgkmcnt(0)" ::: "memory");
  __builtin_amdgcn_s_barrier();

  for (int t = 0; t < 32; ++t) {
    const int cur = t & 1;
    // issue B(t+1) FIRST (oldest of this iter), then R(t+2)
    if (t < 31) {
      const int k0 = (t + 1) * 32;
      gload16(b0 + k0, &Bs[cur ^ 1][ch0 * 512]);
      gload16(b1 + k0, &Bs[cur ^ 1][ch1 * 512]);
    }
    if (t < 30) {
      const float* ap0 = ag0 + (t + 2) * 32;
      const float* ap1 = ag1 + (t + 2) * 32;
      pn0 = *(const f4v*)(ap0); pn1 = *(const f4v*)(ap0 + 4);
      pn2 = *(const f4v*)(ap1); pn3 = *(const f4v*)(ap1 + 4);
    }
    // ---- consume tile t (identical to proven kernel)
    bf16x8 af[4], bfv[4];
    #pragma unroll
    for (int m = 0; m < 4; ++m)
      af[m] = *reinterpret_cast<const bf16x8*>(&As[cur][(wr * 64 + m * 16 + fr) * 32 + kq]);
    #pragma unroll
    for (int n = 0; n < 4; ++n)
      bfv[n] = *reinterpret_cast<const bf16x8*>(&Bs[cur][(wc * 64 + n * 16 + fr) * 32 + kq]);
    #pragma unroll
    for (int m = 0; m < 4; ++m)
      #pragma unroll
      for (int n = 0; n < 4; ++n)
        acc[m][n] = MF(af[m], bfv[n], acc[m][n]);
    // ---- write tile t+1's A (regs loaded last iter) into the other buffer
    if (t < 31) {
      *(bf16x8*)&As[cur ^ 1][w0i] = pk8(pc0, pc1);  // compiler waits R(t+1)
      *(bf16x8*)&As[cur ^ 1][w1i] = pk8(pc2, pc3);
      pc0 = pn0; pc1 = pn1; pc2 = pn2; pc3 = pn3;
      if (t < 30) { asm volatile("s_waitcnt vmcnt(4)" ::: "memory"); }
      else        { asm volatile("s_waitcnt vmcnt(0)" ::: "memory"); }
      asm volatile("s_waitcnt lgkmcnt(0)" ::: "memory");
      __builtin_amdgcn_s_barrier();
    }
  }

  const int row0 = bm * 128 + wr * 64 + (lane >> 4) * 4;
  const int col0 = bn * 128 + wc * 64 + fr;
  #pragma unroll
  for (int m = 0; m < 4; ++m)
    #pragma unroll
    for (int n = 0; n < 4; ++n)
      #pragma unroll
      for (int j = 0; j < 4; ++j)
        Cg[(size_t)(row0 + m * 16 + j) * 1024 + (col0 + n * 16)] = f2bf(acc[m][n][j]);
}

// ---------------------------------------------------------------- GEMM  C = alpha * A . B^T
// MODE 1: causal QK^T, triangular-packed lower-tri tiles, XCD-swizzled.
// MODE 2: causal PV, K clipped to (bm+1)*BM, longest-blocks-first, no swizzle.
#define BM 128
#define BN 128
#define BK 32

template<typename OutT, int MODE>
__global__ __launch_bounds__(256) void gemm_bt(
    const u16* __restrict__ A, const u16* __restrict__ B, OutT* __restrict__ C,
    int K, int lda, int ldb, int ldc,
    size_t sA, size_t sB, size_t sC, float alpha) {
  int bn, bm, bz;
  int kEnd = K;
  if (MODE == 1) {                       // grid 544 = 4 * 136 lower-tri tiles
    int h = blockIdx.x;
    int l = (h & 7) * 68 + (h >> 3);
    bz = l / 136;
    int t = l % 136;
    bm = (int)((sqrtf(8.f * (float)t + 1.f) - 1.f) * 0.5f);
    while ((bm + 1) * (bm + 2) / 2 <= t) ++bm;
    while (bm * (bm + 1) / 2 > t) --bm;
    bn = t - bm * (bm + 1) / 2;
  } else {                               // MODE 2, grid 512
    int l = blockIdx.x;
    bm = 15 - (l >> 5);                  // longest kEnd first
    int rest = l & 31;
    bz = rest >> 3;
    bn = rest & 7;
    kEnd = (K < (bm + 1) * BM) ? K : (bm + 1) * BM;
  }
  const u16* Ag = A + sA * bz + (size_t)bm * BM * lda;
  const u16* Bg = B + sB * bz + (size_t)bn * BN * ldb;
  OutT* Cg = C + sC * bz;

  __shared__ __align__(16) u16 As[2][BM * BK];
  __shared__ __align__(16) u16 Bs[2][BN * BK];

  const int tid = threadIdx.x;
  const int lane = tid & 63, wave = tid >> 6;
  const int wr = wave >> 1, wc = wave & 1;

  const int ch0 = wave, ch1 = wave + 4;
  const int e0 = ch0 * 512 + lane * 8, e1 = ch1 * 512 + lane * 8;
  const int r0 = e0 >> 5, c0 = e0 & 31, r1 = e1 >> 5, c1 = e1 & 31;
  const u16* a0 = Ag + (size_t)r0 * lda + c0;
  const u16* a1 = Ag + (size_t)r1 * lda + c1;
  const u16* b0 = Bg + (size_t)r0 * ldb + c0;
  const u16* b1 = Bg + (size_t)r1 * ldb + c1;

  f32x4 acc[4][4] = {};

  const int fr = lane & 15, kq = (lane >> 4) * 8;
  const int nt = kEnd / BK;

  gload16(a0, &As[0][ch0 * 512]);
  gload16(a1, &As[0][ch1 * 512]);
  gload16(b0, &Bs[0][ch0 * 512]);
  gload16(b1, &Bs[0][ch1 * 512]);
  __syncthreads();

  for (int t = 0; t < nt; ++t) {
    const int cur = t & 1;
    if (t + 1 < nt) {
      const int k0 = (t + 1) * BK;
      gload16(a0 + k0, &As[cur ^ 1][ch0 * 512]);
      gload16(a1 + k0, &As[cur ^ 1][ch1 * 512]);
      gload16(b0 + k0, &Bs[cur ^ 1][ch0 * 512]);
      gload16(b1 + k0, &Bs[cur ^ 1][ch1 * 512]);
    }
    bf16x8 af[4], bfv[4];
    #pragma unroll
    for (int m = 0; m < 4; ++m)
      af[m] = *reinterpret_cast<const bf16x8*>(&As[cur][(wr * 64 + m * 16 + fr) * BK + kq]);
    #pragma unroll
    for (int n = 0; n < 4; ++n)
      bfv[n] = *reinterpret_cast<const bf16x8*>(&Bs[cur][(wc * 64 + n * 16 + fr) * BK + kq]);
    #pragma unroll
    for (int m = 0; m < 4; ++m)
      #pragma unroll
      for (int n = 0; n < 4; ++n)
        acc[m][n] = MF(af[m], bfv[n], acc[m][n]);
    __syncthreads();
  }

  const int row0 = bm * BM + wr * 64 + (lane >> 4) * 4;
  const int col0 = bn * BN + wc * 64 + fr;
  #pragma unroll
  for (int m = 0; m < 4; ++m)
    #pragma unroll
    for (int n = 0; n < 4; ++n) {
      #pragma unroll
      for (int j = 0; j < 4; ++j) {
        float val = acc[m][n][j] * alpha;
        size_t idx = (size_t)(row0 + m * 16 + j) * ldc + (col0 + n * 16);
        if constexpr (sizeof(OutT) == 2) Cg[idx] = f2bf(val);
        else Cg[idx] = val;
      }
    }
}

// ---------------------------------------------------------------- causal softmax (in-place)
// scores: [4][2048][2048] f32. Row r: softmax over t<=s, bf16 P written into the
// same row slot (ldp = 4096 u16). Causal-aware loads/stores.
__global__ __launch_bounds__(256) void softmax_causal(float* __restrict__ sc) {
  int r = blockIdx.x;          // 0..8191
  int s = r & 2047;
  float* row = sc + (size_t)r * 2048;
  int tid = threadIdx.x;
  int t0 = tid * 8;
  f4v x0 = {-1e30f, -1e30f, -1e30f, -1e30f};
  f4v x1 = {-1e30f, -1e30f, -1e30f, -1e30f};
  if (t0 <= s)     x0 = reinterpret_cast<const f4v*>(row)[tid * 2];
  if (t0 + 4 <= s) x1 = reinterpret_cast<const f4v*>(row)[tid * 2 + 1];
  float v[8] = {x0[0], x0[1], x0[2], x0[3], x1[0], x1[1], x1[2], x1[3]};
  float mx = -1e30f;
  #pragma unroll
  for (int j = 0; j < 8; ++j) {
    v[j] = ((t0 + j) <= s) ? v[j] : -1e30f;
    mx = fmaxf(mx, v[j]);
  }
  #pragma unroll
  for (int o = 32; o; o >>= 1) mx = fmaxf(mx, __shfl_xor(mx, o, 64));
  __shared__ float red[8];
  if ((tid & 63) == 0) red[tid >> 6] = mx;
  __syncthreads();
  mx = fmaxf(fmaxf(red[0], red[1]), fmaxf(red[2], red[3]));
  float p[8];
  float sum = 0.f;
  #pragma unroll
  for (int j = 0; j < 8; ++j) {
    p[j] = ((t0 + j) <= s) ? __expf(v[j] - mx) : 0.f;
    sum += p[j];
  }
  #pragma unroll
  for (int o = 32; o; o >>= 1) sum += __shfl_xor(sum, o, 64);
  if ((tid & 63) == 0) red[4 + (tid >> 6)] = sum;
  __syncthreads();
  sum = red[4] + red[5] + red[6] + red[7];
  float inv = 1.0f / sum;
  u16x8 o8;
  #pragma unroll
  for (int j = 0; j < 8; ++j) o8[j] = f2bf(p[j] * inv);
  if (t0 <= (s | 127))   // PV reads cols < (bm+1)*128 only
    reinterpret_cast<u16x8*>(row)[tid] = o8;
}

// ---------------------------------------------------------------- launcher
extern "C" void kernel_launch(void* const* d_in, const int* in_sizes, int n_in,
                              void* d_out, int out_size, void* d_ws, size_t ws_size,
                              hipStream_t stream) {
  const float* q  = (const float*)d_in[0];
  const float* k  = (const float*)d_in[1];
  const float* v  = (const float*)d_in[2];
  // d_in[3] = attn_mask (causal tril) — handled analytically
  const float* Wq = (const float*)d_in[4];
  const float* Wk = (const float*)d_in[5];
  const float* Wv = (const float*)d_in[6];
  float* out = (float*)d_out;
  char* ws = (char*)d_ws;

  const size_t MB = 1024ull * 1024ull;
  // Liveness: Vp & wqb die before sc is written (QK); sc overlays them.
  float* sc = (float*)ws;            // 0..64MB
  u16* Vp  = (u16*)(ws + 0 * MB);    // 16MB (dead after transpose)
  u16* wqb = (u16*)(ws + 16 * MB);   // 6MB  (dead after proj)
  u16* Vt  = (u16*)(ws + 64 * MB);   // 16MB
  u16* Kp  = (u16*)(ws + 80 * MB);   // 16MB
  u16* Qp  = (u16*)(ws + 96 * MB);   // 16MB  -> peak 112MB
  (void)in_sizes; (void)n_in; (void)out_size; (void)ws_size;

  // 1. cast weights only (Q/K/V input cast is fused into the projection)
  cast3_f32_bf16<<<dim3(512, 1, 3), 256, 0, stream>>>(Wq, Wk, Wv, wqb, 1048576);

  // 2. fused-cast projections (1536 blocks, XCD-swizzled, depth-2 reg staging)
  proj_fused<<<1536, 256, 0, stream>>>(q, k, v, wqb, Qp, Kp, Vp);

  // 3. V transpose -> Vt[4][1024][2048]
  transpose_bf16k<<<dim3(16, 32, 4), 256, 0, stream>>>(Vp, Vt);

  // 4. QK^T (scaled, triangular-packed, XCD-swizzled) -> scores f32
  gemm_bt<float, 1><<<544, 256, 0, stream>>>(
      Qp, Kp, sc, 1024, 1024, 1024, 2048,
      (size_t)2048 * 1024, (size_t)2048 * 1024, (size_t)2048 * 2048, 0.03125f);

  // 5. causal softmax, bf16 P written in place (ldp = 4096 u16)
  softmax_causal<<<8192, 256, 0, stream>>>(sc);

  // 6. PV: P[2048][2048](lda 4096) . Vt[1024][2048]^T -> out f32, longest-first
  gemm_bt<float, 2><<<512, 256, 0, stream>>>(
      (u16*)ws, Vt, out, 2048, 4096, 2048, 1024,
      (size_t)2048 * 4096, (size_t)1024 * 2048, (size_t)2048 * 1024, 1.0f);
}